// Round 9
// baseline (1159.240 us; speedup 1.0000x reference)
//
#include <hip/hip_runtime.h>

// Problem constants (match the reference).
#define BB 256
#define TT 2048
#define FF 64
#define UU 64
#define C3 192   // 3*U
#define CH 16    // x_proj rows staged per ring chunk (scan kernel)

__device__ __forceinline__ float readlane_f(float v, int lane) {
    return __int_as_float(__builtin_amdgcn_readlane(__float_as_int(v), lane));
}
// sigmoid/tanh via v_exp/v_rcp; ~1e-6 error, threshold is 2e-2.
__device__ __forceinline__ float fast_sigmoid(float x) {
    return __builtin_amdgcn_rcpf(1.0f + __expf(-x));
}
__device__ __forceinline__ float fast_tanh(float x) {
    return 1.0f - 2.0f * __builtin_amdgcn_rcpf(__expf(2.0f * x) + 1.0f);
}
__device__ __forceinline__ float shflx(float v, int m) { return __shfl_xor(v, m, 64); }

#define REP16(M) M(0) M(1) M(2) M(3) M(4) M(5) M(6) M(7) \
                 M(8) M(9) M(10) M(11) M(12) M(13) M(14) M(15)
#define XREP8(M, I) M(I,0) M(I,1) M(I,2) M(I,3) M(I,4) M(I,5) M(I,6) M(I,7)
#define XREP64(M) XREP8(M,0) XREP8(M,1) XREP8(M,2) XREP8(M,3) \
                  XREP8(M,4) XREP8(M,5) XREP8(M,6) XREP8(M,7)

// ---------------------------------------------------------------------------
// Kernel 1: x_proj chunk = inputs[:, t0:t0+tc, :] @ kernel (+ bias folds).
// xp layout [B][tc][C3], row r = b*tc + tt. Throughput kernel: 2048 waves;
// AGPR spill here is hidden by occupancy (unlike in the serial scan).
// z,r gates: input+recurrent bias folded. h gate: input bias only (the
// recurrent h-bias sits inside r*(.) and is added in the scan).
// ---------------------------------------------------------------------------
__global__ __launch_bounds__(256)
void xproj(const float* __restrict__ in, const float* __restrict__ kmat,
           const float* __restrict__ bias, float* __restrict__ xp,
           int t0, int tc) {
    const int lane = threadIdx.x & 63;
    const int wave = (int)((blockIdx.x * blockDim.x + threadIdx.x) >> 6);
    const int nwaves = (int)((gridDim.x * blockDim.x) >> 6);

#define DECLK(I,J) float kz_##I##J, kr_##I##J, kh_##I##J;
    XREP64(DECLK)
#define INITK(I,J) { const int f_ = (I)*8+(J); \
    kz_##I##J = kmat[f_ * C3 + lane]; \
    kr_##I##J = kmat[f_ * C3 + 64 + lane]; \
    kh_##I##J = kmat[f_ * C3 + 128 + lane]; }
    XREP64(INITK)

    const float bz  = bias[lane]       + bias[C3 + lane];
    const float br  = bias[64 + lane]  + bias[C3 + 64 + lane];
    const float bh0 = bias[128 + lane];

    const int rows = BB * tc;
    for (int r = wave; r < rows; r += nwaves) {
        const int bq = r / tc;
        const int t  = t0 + (r - bq * tc);
        const float a = in[((size_t)bq * TT + t) * FF + lane];
        float az = bz, ar = br, ah = bh0;
#define STEPK(I,J) { const float s_ = readlane_f(a, (I)*8+(J)); \
        az = fmaf(s_, kz_##I##J, az); ar = fmaf(s_, kr_##I##J, ar); \
        ah = fmaf(s_, kh_##I##J, ah); }
        XREP64(STEPK)
        float* o = xp + (size_t)r * C3;
        o[lane] = az; o[64 + lane] = ar; o[128 + lane] = ah;
    }
}

// ---------------------------------------------------------------------------
// Kernel 2: the serial scan, U-weights only (48 resident floats/lane -> fits
// arch VGPRs; the AGPR round-trips that bloated v2/v3/v7's issue count ~2x
// came from holding 96-192 weights).
// Geometry (v7): wave w owns units j in [16w,16w+16); lane = sub*16+u covers
// contraction rows [16sub,16sub+16). Butterfly allreduce (z, r, ah only --
// xh needs no reduction). x rows stream through a 16-step LDS ring staged
// once per CH steps by ALL 256 THREADS (v8 bug: used lane 0..63 -> 3/4 of
// the ring was never written).
// Dropout mask folded into U (mask in {0,2} -> bit-exact).
// ---------------------------------------------------------------------------
__global__ void __launch_bounds__(256, 1)
gru_scan(const float* __restrict__ xp, const float* __restrict__ rk,
         const float* __restrict__ bias, const float* __restrict__ mask,
         const float* __restrict__ dw, const float* __restrict__ db,
         float* __restrict__ hws, float* __restrict__ out,
         int tc, int first, int last) {
    __shared__ __align__(16) float hb[2][64];
    __shared__ __align__(16) float ring[2][CH][C3];   // 24.6 KB

    const int b    = blockIdx.x;
    const int tid  = threadIdx.x;
    const int lane = tid & 63;
    const int wv   = tid >> 6;
    const int sub  = lane >> 4;
    const int u    = lane & 15;
    const int j    = (wv << 4) + u;
    const int i0   = sub << 4;

    // 48 resident weights: U rows i0..i0+15, column j, mask folded.
    const float* mzp = mask;
    const float* mrp = mask + (size_t)BB * UU;
    const float* mhp = mask + (size_t)2 * BB * UU;
#define DECLUW(K) float uz##K, ur##K, uh##K;
    REP16(DECLUW)
#define INITUW(K) { const int i_ = i0 + (K); \
    uz##K = rk[i_ * C3 + j]       * mzp[(size_t)b * UU + i_]; \
    ur##K = rk[i_ * C3 + 64 + j]  * mrp[(size_t)b * UU + i_]; \
    uh##K = rk[i_ * C3 + 128 + j] * mhp[(size_t)b * UU + i_]; }
    REP16(INITUW)

    const float bh1j = bias[C3 + 128 + j];   // recurrent h-bias (inside r)

    const float* __restrict__ xpb = xp + (size_t)b * tc * C3;

    // ---- prologue: stage ring chunk 0 (16 rows = 768 float4, 256 threads
    //      x 3 each); init h.
    {
        const float4* src = (const float4*)xpb;
        const float4 v0 = src[tid], v1 = src[tid + 256], v2 = src[tid + 512];
        float4* dst = (float4*)&ring[0][0][0];
        dst[tid] = v0; dst[tid + 256] = v1; dst[tid + 512] = v2;
    }
    float hown = first ? 0.0f : hws[(size_t)b * UU + j];
    if (wv == 0) hb[0][lane] = first ? 0.0f : hws[(size_t)b * UU + lane];
    __syncthreads();

#pragma unroll 1
    for (int e = 0; e < tc; ++e) {
        const int  c  = e >> 4;
        const bool st = ((e & 15) == 0) && ((c + 1) * CH < tc);

        // ring staging loads: earliest post-barrier point (ALL 256 threads).
        float4 g0, g1, g2;
        if (st) {
            const float4* src = (const float4*)(xpb + (size_t)(c + 1) * CH * C3);
            g0 = src[tid]; g1 = src[tid + 256]; g2 = src[tid + 512];
        }

        // h_e broadcast reads (chain head).
        const float4 hA = *(const float4*)&hb[e & 1][i0];
        const float4 hB = *(const float4*)&hb[e & 1][i0 + 4];
        const float4 hC = *(const float4*)&hb[e & 1][i0 + 8];
        const float4 hD = *(const float4*)&hb[e & 1][i0 + 12];

        // this step's x values (per-unit; no reduction needed).
        const float* xrow = &ring[c & 1][e & 15][0];
        const float xz = xrow[j], xr = xrow[64 + j], xh = xrow[128 + j];

        // 48 h-FMAs.
        float hz = 0.f, hr = 0.f, hah = 0.f;
#define FMA_H(K, HV) { hz = fmaf(HV, uz##K, hz); hr = fmaf(HV, ur##K, hr); \
                       hah = fmaf(HV, uh##K, hah); }
        FMA_H(0,  hA.x) FMA_H(1,  hA.y) FMA_H(2,  hA.z) FMA_H(3,  hA.w)
        FMA_H(4,  hB.x) FMA_H(5,  hB.y) FMA_H(6,  hB.z) FMA_H(7,  hB.w)
        FMA_H(8,  hC.x) FMA_H(9,  hC.y) FMA_H(10, hC.z) FMA_H(11, hC.w)
        FMA_H(12, hD.x) FMA_H(13, hD.y) FMA_H(14, hD.z) FMA_H(15, hD.w)

        // Butterfly allreduce across the 4 sub-blocks (xor 16, then 32).
        float sz = hz, sr = hr, sah = hah;
        { const float t0 = shflx(sz, 16), t1 = shflx(sr, 16), t2 = shflx(sah, 16);
          sz += t0; sr += t1; sah += t2; }
        { const float t0 = shflx(sz, 32), t1 = shflx(sr, 32), t2 = shflx(sah, 32);
          sz += t0; sr += t1; sah += t2; }

        const float z  = fast_sigmoid(sz + xz);
        const float r  = fast_sigmoid(sr + xr);
        const float hh = fast_tanh(fmaf(r, sah + bh1j, xh));
        hown = fmaf(z, hown - hh, hh);            // z*h + (1-z)*hh

        if (sub == 0) hb[(e + 1) & 1][j] = hown;

        // retire ring staging (vmcnt wait overlapped the whole body).
        if (st) {
            float4* dst = (float4*)&ring[(c + 1) & 1][0][0];
            dst[tid] = g0; dst[tid + 256] = g1; dst[tid + 512] = g2;
        }
        __syncthreads();
    }

    if (last) {
        // Dense head: out[b] = h_T @ dense_w + dense_b.
        if (wv == 0) {
            float p = hb[tc & 1][lane] * dw[lane];
#pragma unroll
            for (int o = 32; o > 0; o >>= 1) p += __shfl_down(p, o, 64);
            if (lane == 0) out[b] = p + db[0];
        }
    } else {
        if (wv == 0) hws[(size_t)b * UU + lane] = hb[tc & 1][lane];
    }
}

// ---------------------------------------------------------------------------
// Fallback (ws too small): v7 fused kernel, verbatim (1062 us, correct).
// ---------------------------------------------------------------------------
__global__ void __launch_bounds__(256, 1)
gru_fused7(const float* __restrict__ in, const float* __restrict__ kmat,
           const float* __restrict__ rk, const float* __restrict__ bias,
           const float* __restrict__ mask, const float* __restrict__ dw,
           const float* __restrict__ db, float* __restrict__ out) {
    __shared__ __align__(16) float hb[2][64];
    __shared__ __align__(16) float ab[2][32][FF];

    const int b    = blockIdx.x;
    const int lane = threadIdx.x & 63;
    const int wv   = threadIdx.x >> 6;
    const int sub  = lane >> 4;
    const int u    = lane & 15;
    const int j    = (wv << 4) + u;
    const int i0   = sub << 4;

    const float* mzp = mask;
    const float* mrp = mask + (size_t)BB * UU;
    const float* mhp = mask + (size_t)2 * BB * UU;
#define DECLW7(K) float fuz##K, fur##K, fuh##K, fkz##K, fkr##K, fkh##K;
    REP16(DECLW7)
#define INITW7(K) { const int i_ = i0 + (K); \
    fuz##K = rk[i_ * C3 + j]       * mzp[(size_t)b * UU + i_]; \
    fur##K = rk[i_ * C3 + 64 + j]  * mrp[(size_t)b * UU + i_]; \
    fuh##K = rk[i_ * C3 + 128 + j] * mhp[(size_t)b * UU + i_]; \
    fkz##K = kmat[i_ * C3 + j]; \
    fkr##K = kmat[i_ * C3 + 64 + j]; \
    fkh##K = kmat[i_ * C3 + 128 + j]; }
    REP16(INITW7)

    const float bzj  = bias[j]       + bias[C3 + j];
    const float brj  = bias[64 + j]  + bias[C3 + 64 + j];
    const float bh0j = bias[128 + j];
    const float bh1j = bias[C3 + 128 + j];

    const float* __restrict__ inb = in + (size_t)b * TT * FF;
    {
        const float* src = inb + (size_t)(wv * 8) * FF + lane;
        const float t0 = src[0 * FF], t1 = src[1 * FF], t2 = src[2 * FF],
                    t3 = src[3 * FF], t4 = src[4 * FF], t5 = src[5 * FF],
                    t6 = src[6 * FF], t7 = src[7 * FF];
        float* dst = &ab[0][wv * 8][lane];
        dst[0 * FF] = t0; dst[1 * FF] = t1; dst[2 * FF] = t2; dst[3 * FF] = t3;
        dst[4 * FF] = t4; dst[5 * FF] = t5; dst[6 * FF] = t6; dst[7 * FF] = t7;
    }
    if (wv == 0) hb[0][lane] = 0.0f;
    __syncthreads();

    float4 aA = *(const float4*)&ab[0][0][i0];
    float4 aB = *(const float4*)&ab[0][0][i0 + 4];
    float4 aC = *(const float4*)&ab[0][0][i0 + 8];
    float4 aD = *(const float4*)&ab[0][0][i0 + 12];
    float hown = 0.0f;

#pragma unroll 1
    for (int e = 0; e < TT; ++e) {
        const int  c  = e >> 5;
        const bool st = ((e & 31) == 0) && (c + 1 < TT / 32);
        float g0, g1, g2, g3, g4, g5, g6, g7;
        if (st) {
            const float* src = inb + ((size_t)(c + 1) * 32 + wv * 8) * FF + lane;
            g0 = src[0 * FF]; g1 = src[1 * FF]; g2 = src[2 * FF]; g3 = src[3 * FF];
            g4 = src[4 * FF]; g5 = src[5 * FF]; g6 = src[6 * FF]; g7 = src[7 * FF];
        }
        const float4 hA = *(const float4*)&hb[e & 1][i0];
        const float4 hB = *(const float4*)&hb[e & 1][i0 + 4];
        const float4 hC = *(const float4*)&hb[e & 1][i0 + 8];
        const float4 hD = *(const float4*)&hb[e & 1][i0 + 12];

        float az = 0.f, ar = 0.f, axh = 0.f;
#define FMA_A7(K, AV) { az = fmaf(AV, fkz##K, az); ar = fmaf(AV, fkr##K, ar); \
                        axh = fmaf(AV, fkh##K, axh); }
        FMA_A7(0,  aA.x) FMA_A7(1,  aA.y) FMA_A7(2,  aA.z) FMA_A7(3,  aA.w)
        FMA_A7(4,  aB.x) FMA_A7(5,  aB.y) FMA_A7(6,  aB.z) FMA_A7(7,  aB.w)
        FMA_A7(8,  aC.x) FMA_A7(9,  aC.y) FMA_A7(10, aC.z) FMA_A7(11, aC.w)
        FMA_A7(12, aD.x) FMA_A7(13, aD.y) FMA_A7(14, aD.z) FMA_A7(15, aD.w)

        float hz = 0.f, hr = 0.f, hah = 0.f;
#define FMA_H7(K, HV) { hz = fmaf(HV, fuz##K, hz); hr = fmaf(HV, fur##K, hr); \
                        hah = fmaf(HV, fuh##K, hah); }
        FMA_H7(0,  hA.x) FMA_H7(1,  hA.y) FMA_H7(2,  hA.z) FMA_H7(3,  hA.w)
        FMA_H7(4,  hB.x) FMA_H7(5,  hB.y) FMA_H7(6,  hB.z) FMA_H7(7,  hB.w)
        FMA_H7(8,  hC.x) FMA_H7(9,  hC.y) FMA_H7(10, hC.z) FMA_H7(11, hC.w)
        FMA_H7(12, hD.x) FMA_H7(13, hD.y) FMA_H7(14, hD.z) FMA_H7(15, hD.w)

        float sz = az + hz, sr = ar + hr, sxh = axh, sah = hah;
        { const float t0 = shflx(sz, 16), t1 = shflx(sr, 16),
                      t2 = shflx(sxh, 16), t3 = shflx(sah, 16);
          sz += t0; sr += t1; sxh += t2; sah += t3; }
        { const float t0 = shflx(sz, 32), t1 = shflx(sr, 32),
                      t2 = shflx(sxh, 32), t3 = shflx(sah, 32);
          sz += t0; sr += t1; sxh += t2; sah += t3; }

        const float z  = fast_sigmoid(sz + bzj);
        const float r  = fast_sigmoid(sr + brj);
        const float hh = fast_tanh(fmaf(r, sah + bh1j, sxh + bh0j));
        hown = fmaf(z, hown - hh, hh);
        if (sub == 0) hb[(e + 1) & 1][j] = hown;

        const int rn = (e + 1 < TT) ? (e + 1) : (TT - 1);
        const float* ap = &ab[(rn >> 5) & 1][rn & 31][i0];
        aA = *(const float4*)(ap);
        aB = *(const float4*)(ap + 4);
        aC = *(const float4*)(ap + 8);
        aD = *(const float4*)(ap + 12);

        if (st) {
            float* dst = &ab[(c + 1) & 1][wv * 8][lane];
            dst[0 * FF] = g0; dst[1 * FF] = g1; dst[2 * FF] = g2; dst[3 * FF] = g3;
            dst[4 * FF] = g4; dst[5 * FF] = g5; dst[6 * FF] = g6; dst[7 * FF] = g7;
        }
        __syncthreads();
    }

    if (wv == 0) {
        float p = hb[0][lane] * dw[lane];
#pragma unroll
        for (int o = 32; o > 0; o >>= 1) p += __shfl_down(p, o, 64);
        if (lane == 0) out[b] = p + db[0];
    }
}

// ---------------------------------------------------------------------------
extern "C" void kernel_launch(void* const* d_in, const int* in_sizes, int n_in,
                              void* d_out, int out_size, void* d_ws, size_t ws_size,
                              hipStream_t stream) {
    (void)in_sizes; (void)n_in; (void)out_size;
    const float* inputs = (const float*)d_in[0];
    const float* kmat   = (const float*)d_in[1];
    const float* rk     = (const float*)d_in[2];
    const float* bias   = (const float*)d_in[3];
    const float* dw     = (const float*)d_in[4];
    const float* db     = (const float*)d_in[5];
    const float* mask   = (const float*)d_in[6];
    float* out = (float*)d_out;

    const size_t h_bytes   = (size_t)BB * UU * sizeof(float);   // 64 KB
    const size_t row_bytes = (size_t)BB * C3 * sizeof(float);   // 192 KB / step

    // capacity in timesteps for the xp buffer (multiple of CH)
    int cap = 0;
    if (ws_size > h_bytes)
        cap = (int)((ws_size - h_bytes) / row_bytes) & ~(CH - 1);
    if (cap > TT) cap = TT;

    if (cap >= 256) {
        float* hws = (float*)d_ws;
        float* xp  = (float*)((char*)d_ws + h_bytes);
        const int nch  = (TT + cap - 1) / cap;
        int base = (TT + nch - 1) / nch;
        base = (base + CH - 1) & ~(CH - 1);          // multiple of CH, <= cap
        int t0 = 0;
        while (t0 < TT) {
            const int cur = (TT - t0) < base ? (TT - t0) : base;   // mult of 16
            xproj<<<512, 256, 0, stream>>>(inputs, kmat, bias, xp, t0, cur);
            gru_scan<<<BB, 256, 0, stream>>>(xp, rk, bias, mask, dw, db, hws, out,
                                             cur, t0 == 0 ? 1 : 0,
                                             (t0 + cur == TT) ? 1 : 0);
            t0 += cur;
        }
    } else {
        gru_fused7<<<BB, 256, 0, stream>>>(inputs, kmat, rk, bias, mask, dw, db, out);
    }
}